// Round 1
// baseline (279.494 us; speedup 1.0000x reference)
//
#include <hip/hip_runtime.h>

#define HH 512
#define WW 512
#define NPLANE 48
#define BY 64
#define CHK 16
#define NCH (BY / CHK)   // 4 chunks per block
#define SLOTS 40         // ring slots per col (row r lives at slot r mod 40)
#define KS 11
#define NBLK ((WW / 64) * (HH / BY) * NPLANE)   // 8*8*48 = 3072

typedef __attribute__((ext_vector_type(8))) short short8;   // 8 bf16 (A/B frag)
typedef __attribute__((ext_vector_type(4))) float floatx4;  // 4 fp32 (C/D frag)
typedef __attribute__((ext_vector_type(2))) float float2v;
typedef __attribute__((ext_vector_type(2))) __bf16 bf16x2v;

// exact RNE pack (weights, once)
__device__ inline unsigned pk2bf_rne(float a, float b) {
    union { float f; unsigned u; } ua, ub;
    ua.f = a; ub.f = b;
    unsigned lo = (ua.u + 0x7FFFu + ((ua.u >> 16) & 1u)) >> 16;
    unsigned hi = (ub.u + 0x7FFFu + ((ub.u >> 16) & 1u)) >> 16;
    return lo | (hi << 16);
}

// hot-path pack: float2 -> bf16x2; lowers to v_cvt_pk_bf16_f32 on gfx950
__device__ inline unsigned pkbf(float a, float b) {
    float2v f = {a, b};
    bf16x2v v = __builtin_convertvector(f, bf16x2v);
    return __builtin_bit_cast(unsigned, v);
}

struct Raw { float4 p0, p1, t0, t1; };

// Fully-MFMA SSIM, 4 ring channels: p, t, q=p^2+t^2 (blur linearity: only the
// SUM sigma_p^2+sigma_t^2 is needed), pt. Ring = 20480 B -> exactly 8
// blocks/CU (was 6). BY=64 -> 12 blocks/CU of work over 8 resident.
// Wave-private LDS ring, no barriers in the main loop; v-frag ds_reads precede
// the aliasing h-writes in program order (in-order DS per wave -> WAR safe).
__global__ __launch_bounds__(256, 8) void ssim_kernel(
    const float* __restrict__ pred, const float* __restrict__ target,
    float* __restrict__ ws, float* __restrict__ out)
{
    // ring[wave][ch][col][slot], bf16: 4*4*16*40*2 = 20480 B exactly
    __shared__ __align__(16) short ring[4][4][16][SLOTS];

    const int tid = threadIdx.x;
    const int wv = tid >> 6;
    const int lane = tid & 63;
    const int m = lane & 15;     // A-row / B-col / C-col index
    const int quad = lane >> 4;  // k-group / C-row-group

    // Gaussian weights, sigma=1.5
    float wsum = 0.f;
#pragma unroll
    for (int k = 0; k < KS; ++k) {
        float d = (float)(k - 5);
        wsum += __expf(-d * d * (1.0f / 4.5f));
    }
    const float invs = 1.0f / wsum;

    // Banded weight fragment: value at k=quad*8+j is w[k - m - 3] (0 outside band).
    // Serves as B in h-mfma (B[k][n]=w[k-n-3]) and A in v-mfma (A[m][k]=w[k-m-3]).
    short8 Wf;
    {
        union { short8 v; unsigned u[4]; } W;
#pragma unroll
        for (int jj = 0; jj < 4; ++jj) {
            float v0, v1;
            {
                int idx = quad * 8 + 2 * jj - m - 3;
                float d = (float)(idx - 5);
                v0 = (idx >= 0 && idx < KS) ? __expf(-d * d * (1.0f / 4.5f)) * invs : 0.f;
            }
            {
                int idx = quad * 8 + 2 * jj + 1 - m - 3;
                float d = (float)(idx - 5);
                v1 = (idx >= 0 && idx < KS) ? __expf(-d * d * (1.0f / 4.5f)) * invs : 0.f;
            }
            W.u[jj] = pk2bf_rne(v0, v1);
        }
        Wf = W.v;
    }

    const size_t poff = (size_t)blockIdx.z * HH * WW;
    const float* __restrict__ pp = pred + poff;
    const float* __restrict__ tp = target + poff;
    const int X0 = blockIdx.x * 64 + wv * 16;  // wave's 16-col tile
    const int rawX = X0 - 8;                   // 32-col raw window base
    const int Y0 = blockIdx.y * BY;

    const float C1 = 1.0e-4f;
    const float C2 = 9.0e-4f;
    float lsum = 0.f;
    const floatx4 z = {0.f, 0.f, 0.f, 0.f};

    // load chunk k's raw rows (zero-padded outside the image)
    auto load_raw = [&](int k) -> Raw {
        Raw r;
        r.p0 = make_float4(0, 0, 0, 0); r.p1 = make_float4(0, 0, 0, 0);
        r.t0 = make_float4(0, 0, 0, 0); r.t1 = make_float4(0, 0, 0, 0);
        const int row = Y0 + CHK * k - 8 + m;
        if ((unsigned)row < (unsigned)HH) {
            const float* pr = pp + (size_t)row * WW;
            const float* tr = tp + (size_t)row * WW;
            const int c0 = rawX + quad * 8;
            if ((unsigned)c0 < (unsigned)WW) {
                r.p0 = *(const float4*)(pr + c0);
                r.t0 = *(const float4*)(tr + c0);
            }
            if ((unsigned)(c0 + 4) < (unsigned)WW) {
                r.p1 = *(const float4*)(pr + c0 + 4);
                r.t1 = *(const float4*)(tr + c0 + 4);
            }
        }
        return r;
    };

    // h-step: pack raw -> bf16 frags, 4 MFMA, pack D -> ring at slot base sb
    auto h_step = [&](const Raw& r, int sb) {
        const float p[8] = {r.p0.x, r.p0.y, r.p0.z, r.p0.w,
                            r.p1.x, r.p1.y, r.p1.z, r.p1.w};
        const float t[8] = {r.t0.x, r.t0.y, r.t0.z, r.t0.w,
                            r.t1.x, r.t1.y, r.t1.z, r.t1.w};
        union { short8 v; unsigned u[4]; } Fp, Ft, Fq, Fpt;
#pragma unroll
        for (int jj = 0; jj < 4; ++jj) {
            const float a0 = p[2 * jj], a1 = p[2 * jj + 1];
            const float b0 = t[2 * jj], b1 = t[2 * jj + 1];
            Fp.u[jj]  = pkbf(a0, a1);
            Ft.u[jj]  = pkbf(b0, b1);
            // q = p^2 + t^2 : exact fp32 sum, ONE bf16 quantization
            Fq.u[jj]  = pkbf(fmaf(a0, a0, b0 * b0), fmaf(a1, a1, b1 * b1));
            Fpt.u[jj] = pkbf(a0 * b0, a1 * b1);
        }
        floatx4 Dp  = __builtin_amdgcn_mfma_f32_16x16x32_bf16(Fp.v,  Wf, z, 0, 0, 0);
        floatx4 Dt  = __builtin_amdgcn_mfma_f32_16x16x32_bf16(Ft.v,  Wf, z, 0, 0, 0);
        floatx4 Dq  = __builtin_amdgcn_mfma_f32_16x16x32_bf16(Fq.v,  Wf, z, 0, 0, 0);
        floatx4 Dpt = __builtin_amdgcn_mfma_f32_16x16x32_bf16(Fpt.v, Wf, z, 0, 0, 0);
        // C-layout: col = lane&15 (=m), rows = quad*4 + reg -> slots sb+quad*4+reg
        int slot = sb + quad * 4;
        if (slot >= SLOTS) slot -= SLOTS;
        uint2 v;
        v.x = pkbf(Dp[0], Dp[1]);   v.y = pkbf(Dp[2], Dp[3]);
        *(uint2*)&ring[wv][0][m][slot] = v;
        v.x = pkbf(Dt[0], Dt[1]);   v.y = pkbf(Dt[2], Dt[3]);
        *(uint2*)&ring[wv][1][m][slot] = v;
        v.x = pkbf(Dq[0], Dq[1]);   v.y = pkbf(Dq[2], Dq[3]);
        *(uint2*)&ring[wv][2][m][slot] = v;
        v.x = pkbf(Dpt[0], Dpt[1]); v.y = pkbf(Dpt[2], Dpt[3]);
        *(uint2*)&ring[wv][3][m][slot] = v;
    };

    // Pipeline: prologue h(0),h(1); loop { read v-frags(i); h(i+2); prefetch
    // raw(i+3); v-MFMA + SSIM }. Full unroll (NCH=4): slot arithmetic
    // const-propagates; DS program order preserved (compiler can't prove
    // ring non-aliasing, so v-reads stay ahead of h-writes).
    Raw A = load_raw(0);
    Raw B = load_raw(1);
    Raw C = load_raw(2);
    h_step(A, (0 * CHK + SLOTS - 8) % SLOTS);   // 32
    h_step(B, (1 * CHK + SLOTS - 8) % SLOTS);   // 8
    int hb = (2 * CHK + SLOTS - 8) % SLOTS;     // 24
    int vb = SLOTS - 8;                         // 32
#pragma unroll
    for (int i = 0; i < NCH; ++i) {
        // ---- hoisted v-fragment reads (rows 16i-8 .. 16i+23) ----
        int sq = vb + quad * 8;
        if (sq >= SLOTS) sq -= SLOTS;
        const short8 Bp  = *(const short8*)&ring[wv][0][m][sq];
        const short8 Bt  = *(const short8*)&ring[wv][1][m][sq];
        const short8 Bq  = *(const short8*)&ring[wv][2][m][sq];
        const short8 Bpt = *(const short8*)&ring[wv][3][m][sq];
        vb += CHK; if (vb >= SLOTS) vb -= SLOTS;

        // ---- h-blur chunk i+2 (overlaps the v-read latency) ----
        if (i + 2 <= NCH) {
            h_step(C, hb);
            hb += CHK; if (hb >= SLOTS) hb -= SLOTS;
        }
        if (i + 3 <= NCH) C = load_raw(i + 3);

        // ---- v-blur + SSIM ----
        floatx4 Mp  = __builtin_amdgcn_mfma_f32_16x16x32_bf16(Wf, Bp,  z, 0, 0, 0);
        floatx4 Mt  = __builtin_amdgcn_mfma_f32_16x16x32_bf16(Wf, Bt,  z, 0, 0, 0);
        floatx4 Mq  = __builtin_amdgcn_mfma_f32_16x16x32_bf16(Wf, Bq,  z, 0, 0, 0);
        floatx4 Mpt = __builtin_amdgcn_mfma_f32_16x16x32_bf16(Wf, Bpt, z, 0, 0, 0);
#pragma unroll
        for (int r = 0; r < 4; ++r) {
            const float mup = Mp[r], mut = Mt[r];
            const float mupsq = mup * mup, mutsq = mut * mut, mucr = mup * mut;
            const float scr = Mpt[r] - mucr;
            const float n1 = 2.f * mucr + C1;
            const float n2 = 2.f * scr + C2;
            const float d1 = mupsq + mutsq + C1;
            const float d2 = (Mq[r] - mupsq - mutsq) + C2;  // sp2+st2+C2
            lsum += __fdividef(n1 * n2, d1 * d2);
        }
    }

    // wave reduce -> block reduce through the (now dead, wave-private) ring
#pragma unroll
    for (int off = 32; off > 0; off >>= 1) lsum += __shfl_down(lsum, off, 64);
    if (lane == 0) *(float*)&ring[wv][0][0][0] = lsum;   // own region only
    __syncthreads();
    if (tid == 0) {
        float bsum = *(const float*)&ring[0][0][0][0]
                   + *(const float*)&ring[1][0][0][0]
                   + *(const float*)&ring[2][0][0][0]
                   + *(const float*)&ring[3][0][0][0];
        atomicAdd(&ws[0], bsum);
        __threadfence();                                  // release sum before count
        unsigned old = atomicAdd((unsigned int*)&ws[1], 1u);
        if (old == (unsigned)(NBLK - 1)) {                // fused finalize
            __threadfence();
            float total = atomicAdd(&ws[0], 0.0f);        // coherent RMW read
            out[0] = 1.0f - total * (1.0f / 12582912.0f); // N = 16*3*512*512
        }
    }
}

extern "C" void kernel_launch(void* const* d_in, const int* in_sizes, int n_in,
                              void* d_out, int out_size, void* d_ws, size_t ws_size,
                              hipStream_t stream) {
    const float* pred = (const float*)d_in[0];
    const float* target = (const float*)d_in[1];
    float* out = (float*)d_out;
    float* ws = (float*)d_ws;

    hipMemsetAsync(ws, 0, 2 * sizeof(float), stream);   // sum + block counter
    dim3 grid(WW / 64, HH / BY, NPLANE);                // 8 x 8 x 48 = 3072 blocks
    ssim_kernel<<<grid, 256, 0, stream>>>(pred, target, ws, out);
}

// Round 2
// 276.353 us; speedup vs baseline: 1.0114x; 1.0114x over previous
//
#include <hip/hip_runtime.h>

#define HH 512
#define WW 512
#define NPLANE 48
#define BY 64
#define CHK 16
#define NCH (BY / CHK)   // 4 chunks per block
#define SLOTS 40         // ring slots per col (row r lives at slot r mod 40)
#define KS 11
#define NBLK ((WW / 64) * (HH / BY) * NPLANE)   // 8*8*48 = 3072

typedef __attribute__((ext_vector_type(8))) short short8;   // 8 bf16 (A/B frag)
typedef __attribute__((ext_vector_type(4))) float floatx4;  // 4 fp32 (C/D frag)
typedef __attribute__((ext_vector_type(2))) float float2v;
typedef __attribute__((ext_vector_type(2))) __bf16 bf16x2v;

// exact RNE pack (weights, once)
__device__ inline unsigned pk2bf_rne(float a, float b) {
    union { float f; unsigned u; } ua, ub;
    ua.f = a; ub.f = b;
    unsigned lo = (ua.u + 0x7FFFu + ((ua.u >> 16) & 1u)) >> 16;
    unsigned hi = (ub.u + 0x7FFFu + ((ub.u >> 16) & 1u)) >> 16;
    return lo | (hi << 16);
}

// hot-path pack: float2 -> bf16x2; lowers to v_cvt_pk_bf16_f32 on gfx950
__device__ inline unsigned pkbf(float a, float b) {
    float2v f = {a, b};
    bf16x2v v = __builtin_convertvector(f, bf16x2v);
    return __builtin_bit_cast(unsigned, v);
}

struct Raw { float4 p0, p1, t0, t1; };

// Fully-MFMA SSIM, 4 ring channels: p, t, q=p^2+t^2 (blur linearity: only the
// SUM sigma_p^2+sigma_t^2 is needed), pt. Ring = 20480 B -> exactly 8
// blocks/CU. BY=64 -> 12 blocks/CU of work over 8 resident.
// launch_bounds min-waves stays at 4: bounding to 8 caps regs at 64 and the
// compiler SPILLS the Raw prefetch pipeline (round-1: WRITE_SIZE 48KB->9.4MB,
// dur 55->197us). With cap 128 the 5-ch ancestor fit in 40 regs; 4-ch needs
// less, so HW can still reach 8 waves/SIMD if the allocator lands <=64.
// Wave-private LDS ring, no barriers in the main loop; v-frag ds_reads precede
// the aliasing h-writes in program order (in-order DS per wave -> WAR safe).
__global__ __launch_bounds__(256, 4) void ssim_kernel(
    const float* __restrict__ pred, const float* __restrict__ target,
    float* __restrict__ ws, float* __restrict__ out)
{
    // ring[wave][ch][col][slot], bf16: 4*4*16*40*2 = 20480 B exactly
    __shared__ __align__(16) short ring[4][4][16][SLOTS];

    const int tid = threadIdx.x;
    const int wv = tid >> 6;
    const int lane = tid & 63;
    const int m = lane & 15;     // A-row / B-col / C-col index
    const int quad = lane >> 4;  // k-group / C-row-group

    // Gaussian weights, sigma=1.5
    float wsum = 0.f;
#pragma unroll
    for (int k = 0; k < KS; ++k) {
        float d = (float)(k - 5);
        wsum += __expf(-d * d * (1.0f / 4.5f));
    }
    const float invs = 1.0f / wsum;

    // Banded weight fragment: value at k=quad*8+j is w[k - m - 3] (0 outside band).
    // Serves as B in h-mfma (B[k][n]=w[k-n-3]) and A in v-mfma (A[m][k]=w[k-m-3]).
    short8 Wf;
    {
        union { short8 v; unsigned u[4]; } W;
#pragma unroll
        for (int jj = 0; jj < 4; ++jj) {
            float v0, v1;
            {
                int idx = quad * 8 + 2 * jj - m - 3;
                float d = (float)(idx - 5);
                v0 = (idx >= 0 && idx < KS) ? __expf(-d * d * (1.0f / 4.5f)) * invs : 0.f;
            }
            {
                int idx = quad * 8 + 2 * jj + 1 - m - 3;
                float d = (float)(idx - 5);
                v1 = (idx >= 0 && idx < KS) ? __expf(-d * d * (1.0f / 4.5f)) * invs : 0.f;
            }
            W.u[jj] = pk2bf_rne(v0, v1);
        }
        Wf = W.v;
    }

    const size_t poff = (size_t)blockIdx.z * HH * WW;
    const float* __restrict__ pp = pred + poff;
    const float* __restrict__ tp = target + poff;
    const int X0 = blockIdx.x * 64 + wv * 16;  // wave's 16-col tile
    const int rawX = X0 - 8;                   // 32-col raw window base
    const int Y0 = blockIdx.y * BY;

    const float C1 = 1.0e-4f;
    const float C2 = 9.0e-4f;
    float lsum = 0.f;
    const floatx4 z = {0.f, 0.f, 0.f, 0.f};

    // load chunk k's raw rows (zero-padded outside the image)
    auto load_raw = [&](int k) -> Raw {
        Raw r;
        r.p0 = make_float4(0, 0, 0, 0); r.p1 = make_float4(0, 0, 0, 0);
        r.t0 = make_float4(0, 0, 0, 0); r.t1 = make_float4(0, 0, 0, 0);
        const int row = Y0 + CHK * k - 8 + m;
        if ((unsigned)row < (unsigned)HH) {
            const float* pr = pp + (size_t)row * WW;
            const float* tr = tp + (size_t)row * WW;
            const int c0 = rawX + quad * 8;
            if ((unsigned)c0 < (unsigned)WW) {
                r.p0 = *(const float4*)(pr + c0);
                r.t0 = *(const float4*)(tr + c0);
            }
            if ((unsigned)(c0 + 4) < (unsigned)WW) {
                r.p1 = *(const float4*)(pr + c0 + 4);
                r.t1 = *(const float4*)(tr + c0 + 4);
            }
        }
        return r;
    };

    // h-step: pack raw -> bf16 frags, 4 MFMA, pack D -> ring at slot base sb
    auto h_step = [&](const Raw& r, int sb) {
        const float p[8] = {r.p0.x, r.p0.y, r.p0.z, r.p0.w,
                            r.p1.x, r.p1.y, r.p1.z, r.p1.w};
        const float t[8] = {r.t0.x, r.t0.y, r.t0.z, r.t0.w,
                            r.t1.x, r.t1.y, r.t1.z, r.t1.w};
        union { short8 v; unsigned u[4]; } Fp, Ft, Fq, Fpt;
#pragma unroll
        for (int jj = 0; jj < 4; ++jj) {
            const float a0 = p[2 * jj], a1 = p[2 * jj + 1];
            const float b0 = t[2 * jj], b1 = t[2 * jj + 1];
            Fp.u[jj]  = pkbf(a0, a1);
            Ft.u[jj]  = pkbf(b0, b1);
            // q = p^2 + t^2 : exact fp32 sum, ONE bf16 quantization
            Fq.u[jj]  = pkbf(fmaf(a0, a0, b0 * b0), fmaf(a1, a1, b1 * b1));
            Fpt.u[jj] = pkbf(a0 * b0, a1 * b1);
        }
        floatx4 Dp  = __builtin_amdgcn_mfma_f32_16x16x32_bf16(Fp.v,  Wf, z, 0, 0, 0);
        floatx4 Dt  = __builtin_amdgcn_mfma_f32_16x16x32_bf16(Ft.v,  Wf, z, 0, 0, 0);
        floatx4 Dq  = __builtin_amdgcn_mfma_f32_16x16x32_bf16(Fq.v,  Wf, z, 0, 0, 0);
        floatx4 Dpt = __builtin_amdgcn_mfma_f32_16x16x32_bf16(Fpt.v, Wf, z, 0, 0, 0);
        // C-layout: col = lane&15 (=m), rows = quad*4 + reg -> slots sb+quad*4+reg
        int slot = sb + quad * 4;
        if (slot >= SLOTS) slot -= SLOTS;
        uint2 v;
        v.x = pkbf(Dp[0], Dp[1]);   v.y = pkbf(Dp[2], Dp[3]);
        *(uint2*)&ring[wv][0][m][slot] = v;
        v.x = pkbf(Dt[0], Dt[1]);   v.y = pkbf(Dt[2], Dt[3]);
        *(uint2*)&ring[wv][1][m][slot] = v;
        v.x = pkbf(Dq[0], Dq[1]);   v.y = pkbf(Dq[2], Dq[3]);
        *(uint2*)&ring[wv][2][m][slot] = v;
        v.x = pkbf(Dpt[0], Dpt[1]); v.y = pkbf(Dpt[2], Dpt[3]);
        *(uint2*)&ring[wv][3][m][slot] = v;
    };

    // Pipeline: prologue h(0),h(1); loop { read v-frags(i); h(i+2); prefetch
    // raw(i+3); v-MFMA + SSIM }. unroll 1 (proven): keeps live ranges short so
    // the allocator lands well under the cap; v-reads precede the aliasing
    // h-writes in program order -> in-order DS returns pre-write data.
    Raw A = load_raw(0);
    Raw B = load_raw(1);
    Raw C = load_raw(2);
    h_step(A, (0 * CHK + SLOTS - 8) % SLOTS);   // 32
    h_step(B, (1 * CHK + SLOTS - 8) % SLOTS);   // 8
    int hb = (2 * CHK + SLOTS - 8) % SLOTS;     // 24
    int vb = SLOTS - 8;                         // 32
#pragma unroll 1
    for (int i = 0; i < NCH; ++i) {
        // ---- hoisted v-fragment reads (rows 16i-8 .. 16i+23) ----
        int sq = vb + quad * 8;
        if (sq >= SLOTS) sq -= SLOTS;
        const short8 Bp  = *(const short8*)&ring[wv][0][m][sq];
        const short8 Bt  = *(const short8*)&ring[wv][1][m][sq];
        const short8 Bq  = *(const short8*)&ring[wv][2][m][sq];
        const short8 Bpt = *(const short8*)&ring[wv][3][m][sq];
        vb += CHK; if (vb >= SLOTS) vb -= SLOTS;

        // ---- h-blur chunk i+2 (overlaps the v-read latency) ----
        if (i + 2 <= NCH) {
            h_step(C, hb);
            hb += CHK; if (hb >= SLOTS) hb -= SLOTS;
        }
        if (i + 3 <= NCH) C = load_raw(i + 3);

        // ---- v-blur + SSIM ----
        floatx4 Mp  = __builtin_amdgcn_mfma_f32_16x16x32_bf16(Wf, Bp,  z, 0, 0, 0);
        floatx4 Mt  = __builtin_amdgcn_mfma_f32_16x16x32_bf16(Wf, Bt,  z, 0, 0, 0);
        floatx4 Mq  = __builtin_amdgcn_mfma_f32_16x16x32_bf16(Wf, Bq,  z, 0, 0, 0);
        floatx4 Mpt = __builtin_amdgcn_mfma_f32_16x16x32_bf16(Wf, Bpt, z, 0, 0, 0);
#pragma unroll
        for (int r = 0; r < 4; ++r) {
            const float mup = Mp[r], mut = Mt[r];
            const float mupsq = mup * mup, mutsq = mut * mut, mucr = mup * mut;
            const float scr = Mpt[r] - mucr;
            const float n1 = 2.f * mucr + C1;
            const float n2 = 2.f * scr + C2;
            const float d1 = mupsq + mutsq + C1;
            const float d2 = (Mq[r] - mupsq - mutsq) + C2;  // sp2+st2+C2
            lsum += __fdividef(n1 * n2, d1 * d2);
        }
    }

    // wave reduce -> block reduce through the (now dead, wave-private) ring
#pragma unroll
    for (int off = 32; off > 0; off >>= 1) lsum += __shfl_down(lsum, off, 64);
    if (lane == 0) *(float*)&ring[wv][0][0][0] = lsum;   // own region only
    __syncthreads();
    if (tid == 0) {
        float bsum = *(const float*)&ring[0][0][0][0]
                   + *(const float*)&ring[1][0][0][0]
                   + *(const float*)&ring[2][0][0][0]
                   + *(const float*)&ring[3][0][0][0];
        atomicAdd(&ws[0], bsum);
        __threadfence();                                  // release sum before count
        unsigned old = atomicAdd((unsigned int*)&ws[1], 1u);
        if (old == (unsigned)(NBLK - 1)) {                // fused finalize
            __threadfence();
            float total = atomicAdd(&ws[0], 0.0f);        // coherent RMW read
            out[0] = 1.0f - total * (1.0f / 12582912.0f); // N = 16*3*512*512
        }
    }
}

extern "C" void kernel_launch(void* const* d_in, const int* in_sizes, int n_in,
                              void* d_out, int out_size, void* d_ws, size_t ws_size,
                              hipStream_t stream) {
    const float* pred = (const float*)d_in[0];
    const float* target = (const float*)d_in[1];
    float* out = (float*)d_out;
    float* ws = (float*)d_ws;

    hipMemsetAsync(ws, 0, 2 * sizeof(float), stream);   // sum + block counter
    dim3 grid(WW / 64, HH / BY, NPLANE);                // 8 x 8 x 48 = 3072 blocks
    ssim_kernel<<<grid, 256, 0, stream>>>(pred, target, ws, out);
}

// Round 3
// 148.381 us; speedup vs baseline: 1.8836x; 1.8625x over previous
//
#include <hip/hip_runtime.h>

#define HH 512
#define WW 512
#define NPLANE 48
#define BY 64
#define CHK 16
#define NCH (BY / CHK)   // 4 chunks per block
#define SLOTS 40         // ring slots per col (row r lives at slot r mod 40)
#define KS 11

typedef __attribute__((ext_vector_type(8))) short short8;   // 8 bf16 (A/B frag)
typedef __attribute__((ext_vector_type(4))) float floatx4;  // 4 fp32 (C/D frag)
typedef __attribute__((ext_vector_type(2))) float float2v;
typedef __attribute__((ext_vector_type(2))) __bf16 bf16x2v;

// exact RNE pack (weights, once)
__device__ inline unsigned pk2bf_rne(float a, float b) {
    union { float f; unsigned u; } ua, ub;
    ua.f = a; ub.f = b;
    unsigned lo = (ua.u + 0x7FFFu + ((ua.u >> 16) & 1u)) >> 16;
    unsigned hi = (ub.u + 0x7FFFu + ((ub.u >> 16) & 1u)) >> 16;
    return lo | (hi << 16);
}

// hot-path pack: float2 -> bf16x2; lowers to v_cvt_pk_bf16_f32 on gfx950
__device__ inline unsigned pkbf(float a, float b) {
    float2v f = {a, b};
    bf16x2v v = __builtin_convertvector(f, bf16x2v);
    return __builtin_bit_cast(unsigned, v);
}

struct Raw { float4 p0, p1, t0, t1; };

// Fully-MFMA SSIM, 4 ring channels: p, t, q=p^2+t^2 (blur linearity: only the
// SUM sigma_p^2+sigma_t^2 is ever used), pt. Ring = 20480 B -> exactly 8
// blocks/CU resident. BY=64 -> 12 blocks/CU of work over 8 resident.
//
// EPILOGUE IS FIRE-AND-FORGET ON PURPOSE. Rounds 1-2 fused the finalize via
// atomic sum + __threadfence + same-line counter RMW per block: the fence's
// vmcnt(0) drain + the globally-serialized same-address RMW made each block
// hold its CU slot while waiting -> ~130us of schedule back-pressure
// (dur 55->184us with identical busy-time). One no-return atomicAdd + a
// separate 1-thread finalize kernel is ~3.4x faster end-to-end.
//
// launch_bounds stays (256,4): bounding to 8 caps unified regs at 64 and the
// compiler spills the Raw prefetch pipeline (round 1: WRITE_SIZE 9.4MB).
// Wave-private LDS ring, no barriers in the main loop; v-frag ds_reads precede
// the aliasing h-writes in program order (in-order DS per wave -> WAR safe).
__global__ __launch_bounds__(256, 4) void ssim_kernel(
    const float* __restrict__ pred, const float* __restrict__ target,
    float* __restrict__ ws_sum)
{
    // ring[wave][ch][col][slot], bf16: 4*4*16*40*2 = 20480 B exactly
    __shared__ __align__(16) short ring[4][4][16][SLOTS];

    const int tid = threadIdx.x;
    const int wv = tid >> 6;
    const int lane = tid & 63;
    const int m = lane & 15;     // A-row / B-col / C-col index
    const int quad = lane >> 4;  // k-group / C-row-group

    // Gaussian weights, sigma=1.5
    float wsum = 0.f;
#pragma unroll
    for (int k = 0; k < KS; ++k) {
        float d = (float)(k - 5);
        wsum += __expf(-d * d * (1.0f / 4.5f));
    }
    const float invs = 1.0f / wsum;

    // Banded weight fragment: value at k=quad*8+j is w[k - m - 3] (0 outside band).
    // Serves as B in h-mfma (B[k][n]=w[k-n-3]) and A in v-mfma (A[m][k]=w[k-m-3]).
    short8 Wf;
    {
        union { short8 v; unsigned u[4]; } W;
#pragma unroll
        for (int jj = 0; jj < 4; ++jj) {
            float v0, v1;
            {
                int idx = quad * 8 + 2 * jj - m - 3;
                float d = (float)(idx - 5);
                v0 = (idx >= 0 && idx < KS) ? __expf(-d * d * (1.0f / 4.5f)) * invs : 0.f;
            }
            {
                int idx = quad * 8 + 2 * jj + 1 - m - 3;
                float d = (float)(idx - 5);
                v1 = (idx >= 0 && idx < KS) ? __expf(-d * d * (1.0f / 4.5f)) * invs : 0.f;
            }
            W.u[jj] = pk2bf_rne(v0, v1);
        }
        Wf = W.v;
    }

    const size_t poff = (size_t)blockIdx.z * HH * WW;
    const float* __restrict__ pp = pred + poff;
    const float* __restrict__ tp = target + poff;
    const int X0 = blockIdx.x * 64 + wv * 16;  // wave's 16-col tile
    const int rawX = X0 - 8;                   // 32-col raw window base
    const int Y0 = blockIdx.y * BY;

    const float C1 = 1.0e-4f;
    const float C2 = 9.0e-4f;
    float lsum = 0.f;
    const floatx4 z = {0.f, 0.f, 0.f, 0.f};

    // load chunk k's raw rows (zero-padded outside the image)
    auto load_raw = [&](int k) -> Raw {
        Raw r;
        r.p0 = make_float4(0, 0, 0, 0); r.p1 = make_float4(0, 0, 0, 0);
        r.t0 = make_float4(0, 0, 0, 0); r.t1 = make_float4(0, 0, 0, 0);
        const int row = Y0 + CHK * k - 8 + m;
        if ((unsigned)row < (unsigned)HH) {
            const float* pr = pp + (size_t)row * WW;
            const float* tr = tp + (size_t)row * WW;
            const int c0 = rawX + quad * 8;
            if ((unsigned)c0 < (unsigned)WW) {
                r.p0 = *(const float4*)(pr + c0);
                r.t0 = *(const float4*)(tr + c0);
            }
            if ((unsigned)(c0 + 4) < (unsigned)WW) {
                r.p1 = *(const float4*)(pr + c0 + 4);
                r.t1 = *(const float4*)(tr + c0 + 4);
            }
        }
        return r;
    };

    // h-step: pack raw -> bf16 frags, 4 MFMA, pack D -> ring at slot base sb
    auto h_step = [&](const Raw& r, int sb) {
        const float p[8] = {r.p0.x, r.p0.y, r.p0.z, r.p0.w,
                            r.p1.x, r.p1.y, r.p1.z, r.p1.w};
        const float t[8] = {r.t0.x, r.t0.y, r.t0.z, r.t0.w,
                            r.t1.x, r.t1.y, r.t1.z, r.t1.w};
        union { short8 v; unsigned u[4]; } Fp, Ft, Fq, Fpt;
#pragma unroll
        for (int jj = 0; jj < 4; ++jj) {
            const float a0 = p[2 * jj], a1 = p[2 * jj + 1];
            const float b0 = t[2 * jj], b1 = t[2 * jj + 1];
            Fp.u[jj]  = pkbf(a0, a1);
            Ft.u[jj]  = pkbf(b0, b1);
            // q = p^2 + t^2 : exact fp32 sum, ONE bf16 quantization
            Fq.u[jj]  = pkbf(fmaf(a0, a0, b0 * b0), fmaf(a1, a1, b1 * b1));
            Fpt.u[jj] = pkbf(a0 * b0, a1 * b1);
        }
        floatx4 Dp  = __builtin_amdgcn_mfma_f32_16x16x32_bf16(Fp.v,  Wf, z, 0, 0, 0);
        floatx4 Dt  = __builtin_amdgcn_mfma_f32_16x16x32_bf16(Ft.v,  Wf, z, 0, 0, 0);
        floatx4 Dq  = __builtin_amdgcn_mfma_f32_16x16x32_bf16(Fq.v,  Wf, z, 0, 0, 0);
        floatx4 Dpt = __builtin_amdgcn_mfma_f32_16x16x32_bf16(Fpt.v, Wf, z, 0, 0, 0);
        // C-layout: col = lane&15 (=m), rows = quad*4 + reg -> slots sb+quad*4+reg
        int slot = sb + quad * 4;
        if (slot >= SLOTS) slot -= SLOTS;
        uint2 v;
        v.x = pkbf(Dp[0], Dp[1]);   v.y = pkbf(Dp[2], Dp[3]);
        *(uint2*)&ring[wv][0][m][slot] = v;
        v.x = pkbf(Dt[0], Dt[1]);   v.y = pkbf(Dt[2], Dt[3]);
        *(uint2*)&ring[wv][1][m][slot] = v;
        v.x = pkbf(Dq[0], Dq[1]);   v.y = pkbf(Dq[2], Dq[3]);
        *(uint2*)&ring[wv][2][m][slot] = v;
        v.x = pkbf(Dpt[0], Dpt[1]); v.y = pkbf(Dpt[2], Dpt[3]);
        *(uint2*)&ring[wv][3][m][slot] = v;
    };

    // Pipeline: prologue h(0),h(1); loop { read v-frags(i); h(i+2); prefetch
    // raw(i+3); v-MFMA + SSIM }. unroll 1 (proven): keeps live ranges short so
    // the allocator lands well under the cap; v-reads precede the aliasing
    // h-writes in program order -> in-order DS returns pre-write data.
    Raw A = load_raw(0);
    Raw B = load_raw(1);
    Raw C = load_raw(2);
    h_step(A, (0 * CHK + SLOTS - 8) % SLOTS);   // 32
    h_step(B, (1 * CHK + SLOTS - 8) % SLOTS);   // 8
    int hb = (2 * CHK + SLOTS - 8) % SLOTS;     // 24
    int vb = SLOTS - 8;                         // 32
#pragma unroll 1
    for (int i = 0; i < NCH; ++i) {
        // ---- hoisted v-fragment reads (rows 16i-8 .. 16i+23) ----
        int sq = vb + quad * 8;
        if (sq >= SLOTS) sq -= SLOTS;
        const short8 Bp  = *(const short8*)&ring[wv][0][m][sq];
        const short8 Bt  = *(const short8*)&ring[wv][1][m][sq];
        const short8 Bq  = *(const short8*)&ring[wv][2][m][sq];
        const short8 Bpt = *(const short8*)&ring[wv][3][m][sq];
        vb += CHK; if (vb >= SLOTS) vb -= SLOTS;

        // ---- h-blur chunk i+2 (overlaps the v-read latency) ----
        if (i + 2 <= NCH) {
            h_step(C, hb);
            hb += CHK; if (hb >= SLOTS) hb -= SLOTS;
        }
        if (i + 3 <= NCH) C = load_raw(i + 3);

        // ---- v-blur + SSIM ----
        floatx4 Mp  = __builtin_amdgcn_mfma_f32_16x16x32_bf16(Wf, Bp,  z, 0, 0, 0);
        floatx4 Mt  = __builtin_amdgcn_mfma_f32_16x16x32_bf16(Wf, Bt,  z, 0, 0, 0);
        floatx4 Mq  = __builtin_amdgcn_mfma_f32_16x16x32_bf16(Wf, Bq,  z, 0, 0, 0);
        floatx4 Mpt = __builtin_amdgcn_mfma_f32_16x16x32_bf16(Wf, Bpt, z, 0, 0, 0);
#pragma unroll
        for (int r = 0; r < 4; ++r) {
            const float mup = Mp[r], mut = Mt[r];
            const float mupsq = mup * mup, mutsq = mut * mut, mucr = mup * mut;
            const float scr = Mpt[r] - mucr;
            const float n1 = 2.f * mucr + C1;
            const float n2 = 2.f * scr + C2;
            const float d1 = mupsq + mutsq + C1;
            const float d2 = (Mq[r] - mupsq - mutsq) + C2;  // sp2+st2+C2
            lsum += __fdividef(n1 * n2, d1 * d2);
        }
    }

    // wave reduce -> block reduce through the (now dead, wave-private) ring
    // -> ONE fire-and-forget atomic per block. No fence, no return, no counter:
    // the block retires immediately and frees its CU slot.
#pragma unroll
    for (int off = 32; off > 0; off >>= 1) lsum += __shfl_down(lsum, off, 64);
    if (lane == 0) *(float*)&ring[wv][0][0][0] = lsum;   // own region only
    __syncthreads();
    if (tid == 0) {
        atomicAdd(ws_sum, *(const float*)&ring[0][0][0][0]
                        + *(const float*)&ring[1][0][0][0]
                        + *(const float*)&ring[2][0][0][0]
                        + *(const float*)&ring[3][0][0][0]);
    }
}

__global__ void finalize_kernel(const float* __restrict__ ws_sum,
                                float* __restrict__ out) {
    out[0] = 1.0f - ws_sum[0] * (1.0f / 12582912.0f);  // N = 16*3*512*512
}

extern "C" void kernel_launch(void* const* d_in, const int* in_sizes, int n_in,
                              void* d_out, int out_size, void* d_ws, size_t ws_size,
                              hipStream_t stream) {
    const float* pred = (const float*)d_in[0];
    const float* target = (const float*)d_in[1];
    float* out = (float*)d_out;
    float* ws = (float*)d_ws;

    hipMemsetAsync(ws, 0, sizeof(float), stream);       // graph-capturable
    dim3 grid(WW / 64, HH / BY, NPLANE);                // 8 x 8 x 48 = 3072 blocks
    ssim_kernel<<<grid, 256, 0, stream>>>(pred, target, ws);
    finalize_kernel<<<1, 1, 0, stream>>>(ws, out);
}

// Round 4
// 141.482 us; speedup vs baseline: 1.9755x; 1.0488x over previous
//
#include <hip/hip_runtime.h>

#define HH 512
#define WW 512
#define NPLANE 48
#define BY 128
#define CHK 16
#define NCH (BY / CHK)   // 8 chunks per block
#define SLOTS 40         // ring slots per col (row r lives at slot r mod 40)
#define KS 11

typedef __attribute__((ext_vector_type(8))) short short8;   // 8 bf16 (A/B frag)
typedef __attribute__((ext_vector_type(4))) float floatx4;  // 4 fp32 (C/D frag)
typedef __attribute__((ext_vector_type(2))) float float2v;
typedef __attribute__((ext_vector_type(2))) __bf16 bf16x2v;

// exact RNE pack (weights, once)
__device__ inline unsigned pk2bf_rne(float a, float b) {
    union { float f; unsigned u; } ua, ub;
    ua.f = a; ub.f = b;
    unsigned lo = (ua.u + 0x7FFFu + ((ua.u >> 16) & 1u)) >> 16;
    unsigned hi = (ub.u + 0x7FFFu + ((ub.u >> 16) & 1u)) >> 16;
    return lo | (hi << 16);
}

// hot-path pack: float2 -> bf16x2; lowers to v_cvt_pk_bf16_f32 on gfx950
__device__ inline unsigned pkbf(float a, float b) {
    float2v f = {a, b};
    bf16x2v v = __builtin_convertvector(f, bf16x2v);
    return __builtin_bit_cast(unsigned, v);
}

struct Raw { float4 p0, p1, t0, t1; };

// Fully-MFMA SSIM, 4 ring channels: p, t, q=p^2+t^2 (blur linearity: only the
// SUM sigma_p^2+sigma_t^2 is ever used), pt. Ring = 20480 B.
//
// Geometry: BY=128 (round-3's BY=64 doubled the per-block prologue and raised
// the y-halo h-step fraction 1.125->1.25; its 12-over-8 oversubscription never
// showed up as latency hiding -> net wash vs round 0). 1536 blocks = 6/CU of
// work, all resident (LDS cap 8), launched at t=0.
//
// Raw prefetch is 2 chunks deep (C,D): load-to-use distance = 2 iterations,
// ~2x the HBM-latency cover and 2x the bytes in flight per wave (the kernel is
// HBM-latency-bound: both pipes <35%, HBM 24%). +16 VGPR, ~52 total <= 64.
//
// EPILOGUE IS FIRE-AND-FORGET ON PURPOSE. Rounds 1-2 fused the finalize via
// atomic sum + __threadfence + same-line counter RMW per block: the fence's
// vmcnt(0) drain + globally-serialized RMW made each block hold its CU slot
// -> ~130us back-pressure (dur 55->184us, identical busy-time). One no-return
// atomicAdd + a separate 1-thread finalize kernel is ~3.4x faster.
//
// launch_bounds stays (256,4): bounding to 8 caps unified regs at 64 and the
// compiler spills the Raw prefetch pipeline (round 1: WRITE_SIZE 9.4MB).
// Wave-private LDS ring, no barriers in the main loop; v-frag ds_reads precede
// the aliasing h-writes in program order (in-order DS per wave -> WAR safe).
__global__ __launch_bounds__(256, 4) void ssim_kernel(
    const float* __restrict__ pred, const float* __restrict__ target,
    float* __restrict__ ws_sum)
{
    // ring[wave][ch][col][slot], bf16: 4*4*16*40*2 = 20480 B exactly
    __shared__ __align__(16) short ring[4][4][16][SLOTS];

    const int tid = threadIdx.x;
    const int wv = tid >> 6;
    const int lane = tid & 63;
    const int m = lane & 15;     // A-row / B-col / C-col index
    const int quad = lane >> 4;  // k-group / C-row-group

    // Gaussian weights, sigma=1.5
    float wsum = 0.f;
#pragma unroll
    for (int k = 0; k < KS; ++k) {
        float d = (float)(k - 5);
        wsum += __expf(-d * d * (1.0f / 4.5f));
    }
    const float invs = 1.0f / wsum;

    // Banded weight fragment: value at k=quad*8+j is w[k - m - 3] (0 outside band).
    // Serves as B in h-mfma (B[k][n]=w[k-n-3]) and A in v-mfma (A[m][k]=w[k-m-3]).
    short8 Wf;
    {
        union { short8 v; unsigned u[4]; } W;
#pragma unroll
        for (int jj = 0; jj < 4; ++jj) {
            float v0, v1;
            {
                int idx = quad * 8 + 2 * jj - m - 3;
                float d = (float)(idx - 5);
                v0 = (idx >= 0 && idx < KS) ? __expf(-d * d * (1.0f / 4.5f)) * invs : 0.f;
            }
            {
                int idx = quad * 8 + 2 * jj + 1 - m - 3;
                float d = (float)(idx - 5);
                v1 = (idx >= 0 && idx < KS) ? __expf(-d * d * (1.0f / 4.5f)) * invs : 0.f;
            }
            W.u[jj] = pk2bf_rne(v0, v1);
        }
        Wf = W.v;
    }

    const size_t poff = (size_t)blockIdx.z * HH * WW;
    const float* __restrict__ pp = pred + poff;
    const float* __restrict__ tp = target + poff;
    const int X0 = blockIdx.x * 64 + wv * 16;  // wave's 16-col tile
    const int rawX = X0 - 8;                   // 32-col raw window base
    const int Y0 = blockIdx.y * BY;

    const float C1 = 1.0e-4f;
    const float C2 = 9.0e-4f;
    float lsum = 0.f;
    const floatx4 z = {0.f, 0.f, 0.f, 0.f};

    // load chunk k's raw rows (zero-padded outside the image)
    auto load_raw = [&](int k) -> Raw {
        Raw r;
        r.p0 = make_float4(0, 0, 0, 0); r.p1 = make_float4(0, 0, 0, 0);
        r.t0 = make_float4(0, 0, 0, 0); r.t1 = make_float4(0, 0, 0, 0);
        const int row = Y0 + CHK * k - 8 + m;
        if ((unsigned)row < (unsigned)HH) {
            const float* pr = pp + (size_t)row * WW;
            const float* tr = tp + (size_t)row * WW;
            const int c0 = rawX + quad * 8;
            if ((unsigned)c0 < (unsigned)WW) {
                r.p0 = *(const float4*)(pr + c0);
                r.t0 = *(const float4*)(tr + c0);
            }
            if ((unsigned)(c0 + 4) < (unsigned)WW) {
                r.p1 = *(const float4*)(pr + c0 + 4);
                r.t1 = *(const float4*)(tr + c0 + 4);
            }
        }
        return r;
    };

    // h-step: pack raw -> bf16 frags, 4 MFMA, pack D -> ring at slot base sb
    auto h_step = [&](const Raw& r, int sb) {
        const float p[8] = {r.p0.x, r.p0.y, r.p0.z, r.p0.w,
                            r.p1.x, r.p1.y, r.p1.z, r.p1.w};
        const float t[8] = {r.t0.x, r.t0.y, r.t0.z, r.t0.w,
                            r.t1.x, r.t1.y, r.t1.z, r.t1.w};
        union { short8 v; unsigned u[4]; } Fp, Ft, Fq, Fpt;
#pragma unroll
        for (int jj = 0; jj < 4; ++jj) {
            const float a0 = p[2 * jj], a1 = p[2 * jj + 1];
            const float b0 = t[2 * jj], b1 = t[2 * jj + 1];
            Fp.u[jj]  = pkbf(a0, a1);
            Ft.u[jj]  = pkbf(b0, b1);
            // q = p^2 + t^2 : exact fp32 sum, ONE bf16 quantization
            Fq.u[jj]  = pkbf(fmaf(a0, a0, b0 * b0), fmaf(a1, a1, b1 * b1));
            Fpt.u[jj] = pkbf(a0 * b0, a1 * b1);
        }
        floatx4 Dp  = __builtin_amdgcn_mfma_f32_16x16x32_bf16(Fp.v,  Wf, z, 0, 0, 0);
        floatx4 Dt  = __builtin_amdgcn_mfma_f32_16x16x32_bf16(Ft.v,  Wf, z, 0, 0, 0);
        floatx4 Dq  = __builtin_amdgcn_mfma_f32_16x16x32_bf16(Fq.v,  Wf, z, 0, 0, 0);
        floatx4 Dpt = __builtin_amdgcn_mfma_f32_16x16x32_bf16(Fpt.v, Wf, z, 0, 0, 0);
        // C-layout: col = lane&15 (=m), rows = quad*4 + reg -> slots sb+quad*4+reg
        int slot = sb + quad * 4;
        if (slot >= SLOTS) slot -= SLOTS;
        uint2 v;
        v.x = pkbf(Dp[0], Dp[1]);   v.y = pkbf(Dp[2], Dp[3]);
        *(uint2*)&ring[wv][0][m][slot] = v;
        v.x = pkbf(Dt[0], Dt[1]);   v.y = pkbf(Dt[2], Dt[3]);
        *(uint2*)&ring[wv][1][m][slot] = v;
        v.x = pkbf(Dq[0], Dq[1]);   v.y = pkbf(Dq[2], Dq[3]);
        *(uint2*)&ring[wv][2][m][slot] = v;
        v.x = pkbf(Dpt[0], Dpt[1]); v.y = pkbf(Dpt[2], Dpt[3]);
        *(uint2*)&ring[wv][3][m][slot] = v;
    };

    // Pipeline: prologue h(0),h(1); loop { read v-frags(i); h(i+2) from C;
    // rotate C<-D; prefetch D = raw(i+4); v-MFMA + SSIM }. unroll 1 (proven):
    // keeps live ranges short; v-reads precede the aliasing h-writes in
    // program order -> in-order DS returns pre-write data (wave-private ring).
    Raw A = load_raw(0);
    Raw B = load_raw(1);
    Raw C = load_raw(2);
    Raw D = load_raw(3);
    h_step(A, (0 * CHK + SLOTS - 8) % SLOTS);   // 32
    h_step(B, (1 * CHK + SLOTS - 8) % SLOTS);   // 8
    int hb = (2 * CHK + SLOTS - 8) % SLOTS;     // 24
    int vb = SLOTS - 8;                         // 32
#pragma unroll 1
    for (int i = 0; i < NCH; ++i) {
        // ---- hoisted v-fragment reads (rows 16i-8 .. 16i+23) ----
        int sq = vb + quad * 8;
        if (sq >= SLOTS) sq -= SLOTS;
        const short8 Bp  = *(const short8*)&ring[wv][0][m][sq];
        const short8 Bt  = *(const short8*)&ring[wv][1][m][sq];
        const short8 Bq  = *(const short8*)&ring[wv][2][m][sq];
        const short8 Bpt = *(const short8*)&ring[wv][3][m][sq];
        vb += CHK; if (vb >= SLOTS) vb -= SLOTS;

        // ---- h-blur chunk i+2 (overlaps the v-read latency) ----
        if (i + 2 <= NCH) {
            h_step(C, hb);
            hb += CHK; if (hb >= SLOTS) hb -= SLOTS;
            C = D;
        }
        if (i + 4 <= NCH) D = load_raw(i + 4);

        // ---- v-blur + SSIM ----
        floatx4 Mp  = __builtin_amdgcn_mfma_f32_16x16x32_bf16(Wf, Bp,  z, 0, 0, 0);
        floatx4 Mt  = __builtin_amdgcn_mfma_f32_16x16x32_bf16(Wf, Bt,  z, 0, 0, 0);
        floatx4 Mq  = __builtin_amdgcn_mfma_f32_16x16x32_bf16(Wf, Bq,  z, 0, 0, 0);
        floatx4 Mpt = __builtin_amdgcn_mfma_f32_16x16x32_bf16(Wf, Bpt, z, 0, 0, 0);
#pragma unroll
        for (int r = 0; r < 4; ++r) {
            const float mup = Mp[r], mut = Mt[r];
            const float mupsq = mup * mup, mutsq = mut * mut, mucr = mup * mut;
            const float scr = Mpt[r] - mucr;
            const float n1 = 2.f * mucr + C1;
            const float n2 = 2.f * scr + C2;
            const float d1 = mupsq + mutsq + C1;
            const float d2 = (Mq[r] - mupsq - mutsq) + C2;  // sp2+st2+C2
            lsum += __fdividef(n1 * n2, d1 * d2);
        }
    }

    // wave reduce -> block reduce through the (now dead, wave-private) ring
    // -> ONE fire-and-forget atomic per block. No fence, no return, no counter.
#pragma unroll
    for (int off = 32; off > 0; off >>= 1) lsum += __shfl_down(lsum, off, 64);
    if (lane == 0) *(float*)&ring[wv][0][0][0] = lsum;   // own region only
    __syncthreads();
    if (tid == 0) {
        atomicAdd(ws_sum, *(const float*)&ring[0][0][0][0]
                        + *(const float*)&ring[1][0][0][0]
                        + *(const float*)&ring[2][0][0][0]
                        + *(const float*)&ring[3][0][0][0]);
    }
}

__global__ void finalize_kernel(const float* __restrict__ ws_sum,
                                float* __restrict__ out) {
    out[0] = 1.0f - ws_sum[0] * (1.0f / 12582912.0f);  // N = 16*3*512*512
}

extern "C" void kernel_launch(void* const* d_in, const int* in_sizes, int n_in,
                              void* d_out, int out_size, void* d_ws, size_t ws_size,
                              hipStream_t stream) {
    const float* pred = (const float*)d_in[0];
    const float* target = (const float*)d_in[1];
    float* out = (float*)d_out;
    float* ws = (float*)d_ws;

    hipMemsetAsync(ws, 0, sizeof(float), stream);       // graph-capturable
    dim3 grid(WW / 64, HH / BY, NPLANE);                // 8 x 4 x 48 = 1536 blocks
    ssim_kernel<<<grid, 256, 0, stream>>>(pred, target, ws);
    finalize_kernel<<<1, 1, 0, stream>>>(ws, out);
}